// Round 5
// baseline (110.605 us; speedup 1.0000x reference)
//
#include <hip/hip_runtime.h>
#include <math.h>

#define N_PYR 30000
#define N_PV  3000
#define N_SST 2250
#define N_VIP 1500
#define N_NGC 750
#define N_BIG (N_VIP + N_NGC)   // 2250 big rows (K = 30000)

#define DT    0.5f
#define E_E   3.0f
#define E_I   (-0.5f)
#define NIC_DECAY 0.9900498337491681f   // exp(-0.5/50)
#define MUS_DECAY 0.9975031223974601f   // exp(-0.5/200)

// matvec: one wave per (row, chunk) unit.
// Big rows: 4 K-chunks of 7500 floats; block = 4 rows x same chunk.
//   563 quads x 4 chunks = 2252 blocks (last quad has 2 real rows).
// Gap rows: full K=3000; block = 4 rows. 750 blocks.
#define N_CHUNKS    4
#define KCHUNK      (N_PYR / N_CHUNKS)       // 7500 floats = 30000 B
#define BIG_QUADS   ((N_BIG + 3) / 4)        // 563
#define BIG_BLOCKS  (BIG_QUADS * N_CHUNKS)   // 2252
#define GAP_BLOCKS  (N_PV / 4)               // 750

// Pieces: 1 KB each (64 lanes x 16 B). Pipeline depth 4, 8 slots (2D) per wave.
#define NP_BIG   30   // 29 full + tail of 304 B (19 lanes)
#define TL_BIG   19
#define NP_GAP   12   // 11 full + tail of 736 B (46 lanes)
#define TL_GAP   46

// ws layout (12000 floats, same as R4):
//   [chunk*2250 + r] chunk=0..3, big-row partials
//   [9000 + j]       pv_gap results
#define WS_GAP (N_CHUNKS * N_BIG)

#define WAITVM(N) asm volatile("s_waitcnt vmcnt(" #N ")" ::: "memory")

__device__ __forceinline__ float dot4(const float4 w, const float4 x) {
    return w.x * x.x + w.y * x.y + w.z * x.z + w.w * x.w;
}
__device__ __forceinline__ float sum4(const float4 w) {
    return w.x + w.y + w.z + w.w;
}

__device__ __forceinline__ void load_lds16(const void* gsrc, void* lds_dst) {
    __builtin_amdgcn_global_load_lds(
        (const __attribute__((address_space(1))) void*)gsrc,
        (__attribute__((address_space(3))) void*)lds_dst, 16, 0, 0);
}

__global__ __launch_bounds__(256) void matvec_k(
    const float* __restrict__ w_vip, const float* __restrict__ w_ngc,
    const float* __restrict__ w_gap, const float* __restrict__ lre,
    const float* __restrict__ prev, float* __restrict__ ws)
{
    __shared__ float4 xs[KCHUNK / 4];   // 1875 float4 = 30 KB (gap uses 750)
    __shared__ float4 wsl[4][512];      // 4 waves x 8 slots x 64 float4 = 32 KB

    const int b = blockIdx.x;
    const int t = threadIdx.x;
    const int wv = t >> 6;     // wave id 0..3
    const int lane = t & 63;

    const float* wrow;         // this wave's weight-unit base
    const float* xsrc;         // x chunk base
    int xn4, NP, tailL, r, dst;
    bool is_gap, valid = true;

    if (b < BIG_BLOCKS) {
        const int q = b >> 2, chunk = b & 3;
        r = 4 * q + wv;
        if (r >= N_BIG) { r = N_BIG - 1; valid = false; }
        const float* base = (r < N_VIP)
            ? (w_vip + (size_t)r * N_PYR)
            : (w_ngc + (size_t)(r - N_VIP) * N_PYR);
        wrow = base + chunk * KCHUNK;
        xsrc = lre + chunk * KCHUNK;
        xn4 = KCHUNK / 4;          // 1875
        NP = NP_BIG; tailL = TL_BIG;
        dst = chunk * N_BIG + r;
        is_gap = false;
    } else {
        const int g = b - BIG_BLOCKS;
        r = 4 * g + wv;
        wrow = w_gap + (size_t)r * N_PV;
        xsrc = prev;
        xn4 = N_PV / 4;            // 750
        NP = NP_GAP; tailL = TL_GAP;
        dst = WS_GAP + r;
        is_gap = true;
    }

    // -------- stage x chunk into LDS (cooperative, all 256 threads) --------
    {
        const float4* xv4 = (const float4*)xsrc;
        for (int i = t; i < xn4; i += 256) xs[i] = xv4[i];
    }

    // -------- prologue: DMA first 4 weight pieces for this wave --------
    const char* gbase = (const char*)wrow + lane * 16;
    char* lbase = (char*)&wsl[wv][0];
    #pragma unroll
    for (int p = 0; p < 4; ++p)
        load_lds16(gbase + p * 1024, lbase + p * 1024);

    __syncthreads();   // x ready for all waves (also drains vmcnt)

    float acc = 0.0f, sac = 0.0f;

    #define ISSUE(P) do {                                                   \
        const int p_ = (P);                                                 \
        const char* s_ = gbase + p_ * 1024;                                 \
        if (p_ == NP - 1 && lane >= tailL) s_ = (const char*)wrow;          \
        load_lds16(s_, lbase + (p_ & 7) * 1024);                            \
    } while (0)

    #define CONSUME(P, NL) do {                                             \
        const int p_ = (P);                                                 \
        if (lane < (NL)) {                                                  \
            const float4 wq = wsl[wv][(p_ & 7) * 64 + lane];                \
            const float4 xq = xs[p_ * 64 + lane];                           \
            acc += dot4(wq, xq);                                            \
            if (is_gap) sac += sum4(wq);                                    \
        }                                                                   \
    } while (0)

    // steady state: issue piece p+4, wait until piece p arrived, consume
    for (int p = 0; p < NP - 4; ++p) {
        ISSUE(p + 4);
        WAITVM(4);
        CONSUME(p, 64);
    }
    WAITVM(3); CONSUME(NP - 4, 64);
    WAITVM(2); CONSUME(NP - 3, 64);
    WAITVM(1); CONSUME(NP - 2, 64);
    WAITVM(0); CONSUME(NP - 1, tailL);

    // -------- wave reduction --------
    #pragma unroll
    for (int off = 32; off > 0; off >>= 1) {
        acc += __shfl_down(acc, off, 64);
        sac += __shfl_down(sac, off, 64);
    }

    if (lane == 0 && valid) {
        float res = acc;
        if (is_gap) res = acc - prev[r] * sac;
        ws[dst] = res;
    }

    #undef ISSUE
    #undef CONSUME
}

// ---------------------------------------------------------------------------
// Kernel 2: LIF update for all 7500 interneurons.
// ---------------------------------------------------------------------------
struct LifArgs {
    const float *pv_g_exc, *pv_g_inh, *sst_g_exc, *sst_g_inh;
    const float *vip_g_exc, *vip_g_inh, *ngc_g_exc, *ngc_g_inh;
    const float *ffe, *ach, *nic, *mus;
    const float *pv_gL, *pv_tau, *pv_vth, *pv_v, *pv_ad;
    const float *sst_gL, *sst_tau, *sst_vth, *sst_v, *sst_ad;
    const float *vip_gL, *vip_tau, *vip_vth, *vip_v, *vip_ad;
    const float *ngc_gL, *ngc_tau, *ngc_vth, *ngc_v, *ngc_ad;
    const float *ws;
    float *out;
};

__device__ __forceinline__ void lif_step(
    float v, float adapt, float gE, float gI, float iex,
    float gL, float tau, float vth, float& spk, float& vout)
{
    const float C = gL * tau;
    const float I = gL * (0.0f - v) + gE * (E_E - v) + gI * (E_I - v) + iex;
    const float v_new = v + DT * I / C;
    spk = (v_new >= vth + adapt) ? 1.0f : 0.0f;
    vout = (spk > 0.0f) ? 0.0f : v_new;
}

__global__ __launch_bounds__(256) void lif_k(LifArgs a)
{
    const int i = blockIdx.x * 256 + threadIdx.x;
    const int total = N_PV + N_SST + N_VIP + N_NGC;  // 7500
    if (i >= total) return;

    float spk, vout;
    if (i < N_PV) {
        const int j = i;
        const float gE = a.pv_g_exc[j] + a.ffe[j];
        const float iex = a.ws[WS_GAP + j];
        lif_step(a.pv_v[j], a.pv_ad[j], gE, a.pv_g_inh[j], iex,
                 a.pv_gL[j], a.pv_tau[j], a.pv_vth[j], spk, vout);
        a.out[j] = spk;
        a.out[total + j] = vout;
    } else if (i < N_PV + N_SST) {
        const int j = i - N_PV;
        lif_step(a.sst_v[j], a.sst_ad[j], a.sst_g_exc[j], a.sst_g_inh[j], 0.0f,
                 a.sst_gL[j], a.sst_tau[j], a.sst_vth[j], spk, vout);
        a.out[N_PV + j] = spk;
        a.out[total + N_PV + j] = vout;
    } else if (i < N_PV + N_SST + N_VIP) {
        const int j = i - N_PV - N_SST;
        const float nic = a.nic[j] * NIC_DECAY + a.ach[0];
        const float lr = a.ws[j] + a.ws[N_BIG + j]
                       + a.ws[2 * N_BIG + j] + a.ws[3 * N_BIG + j];
        const float gE = a.vip_g_exc[j] + lr + nic * 0.25f;
        lif_step(a.vip_v[j], a.vip_ad[j], gE, a.vip_g_inh[j], 0.0f,
                 a.vip_gL[j], a.vip_tau[j], a.vip_vth[j], spk, vout);
        a.out[N_PV + N_SST + j] = spk;
        a.out[total + N_PV + N_SST + j] = vout;
    } else {
        const int j = i - N_PV - N_SST - N_VIP;
        const float mus = a.mus[j] * MUS_DECAY + a.ach[0];
        const int r = N_VIP + j;
        const float lr = a.ws[r] + a.ws[N_BIG + r]
                       + a.ws[2 * N_BIG + r] + a.ws[3 * N_BIG + r];
        const float gE = a.ngc_g_exc[j] + lr + mus * 0.2f;
        lif_step(a.ngc_v[j], a.ngc_ad[j], gE, a.ngc_g_inh[j], 0.0f,
                 a.ngc_gL[j], a.ngc_tau[j], a.ngc_vth[j], spk, vout);
        a.out[N_PV + N_SST + N_VIP + j] = spk;
        a.out[total + N_PV + N_SST + N_VIP + j] = vout;
    }
}

extern "C" void kernel_launch(void* const* d_in, const int* in_sizes, int n_in,
                              void* d_out, int out_size, void* d_ws, size_t ws_size,
                              hipStream_t stream) {
    const float* pv_g_exc  = (const float*)d_in[0];
    const float* pv_g_inh  = (const float*)d_in[1];
    const float* sst_g_exc = (const float*)d_in[2];
    const float* sst_g_inh = (const float*)d_in[3];
    const float* vip_g_exc = (const float*)d_in[4];
    const float* vip_g_inh = (const float*)d_in[5];
    const float* ngc_g_exc = (const float*)d_in[6];
    const float* ngc_g_inh = (const float*)d_in[7];
    const float* ffe       = (const float*)d_in[8];
    const float* lre       = (const float*)d_in[9];
    const float* ach       = (const float*)d_in[10];
    const float* w_lr_vip  = (const float*)d_in[11];
    const float* w_lr_ngc  = (const float*)d_in[12];
    const float* w_pv_gap  = (const float*)d_in[13];
    const float* prev_pv   = (const float*)d_in[14];
    const float* nic_trace = (const float*)d_in[15];
    const float* mus_trace = (const float*)d_in[16];

    const float* pv_gL   = (const float*)d_in[17];
    const float* pv_tau  = (const float*)d_in[18];
    const float* pv_vth  = (const float*)d_in[19];
    const float* pv_v    = (const float*)d_in[21];
    const float* pv_ad   = (const float*)d_in[22];

    const float* sst_gL   = (const float*)d_in[23];
    const float* sst_tau  = (const float*)d_in[24];
    const float* sst_vth  = (const float*)d_in[25];
    const float* sst_v    = (const float*)d_in[27];
    const float* sst_ad   = (const float*)d_in[28];

    const float* vip_gL   = (const float*)d_in[29];
    const float* vip_tau  = (const float*)d_in[30];
    const float* vip_vth  = (const float*)d_in[31];
    const float* vip_v    = (const float*)d_in[33];
    const float* vip_ad   = (const float*)d_in[34];

    const float* ngc_gL   = (const float*)d_in[35];
    const float* ngc_tau  = (const float*)d_in[36];
    const float* ngc_vth  = (const float*)d_in[37];
    const float* ngc_v    = (const float*)d_in[39];
    const float* ngc_ad   = (const float*)d_in[40];

    float* ws  = (float*)d_ws;
    float* out = (float*)d_out;

    matvec_k<<<BIG_BLOCKS + GAP_BLOCKS, 256, 0, stream>>>(
        w_lr_vip, w_lr_ngc, w_pv_gap, lre, prev_pv, ws);

    LifArgs a;
    a.pv_g_exc = pv_g_exc; a.pv_g_inh = pv_g_inh;
    a.sst_g_exc = sst_g_exc; a.sst_g_inh = sst_g_inh;
    a.vip_g_exc = vip_g_exc; a.vip_g_inh = vip_g_inh;
    a.ngc_g_exc = ngc_g_exc; a.ngc_g_inh = ngc_g_inh;
    a.ffe = ffe; a.ach = ach; a.nic = nic_trace; a.mus = mus_trace;
    a.pv_gL = pv_gL; a.pv_tau = pv_tau; a.pv_vth = pv_vth;
    a.pv_v = pv_v; a.pv_ad = pv_ad;
    a.sst_gL = sst_gL; a.sst_tau = sst_tau; a.sst_vth = sst_vth;
    a.sst_v = sst_v; a.sst_ad = sst_ad;
    a.vip_gL = vip_gL; a.vip_tau = vip_tau; a.vip_vth = vip_vth;
    a.vip_v = vip_v; a.vip_ad = vip_ad;
    a.ngc_gL = ngc_gL; a.ngc_tau = ngc_tau; a.ngc_vth = ngc_vth;
    a.ngc_v = ngc_v; a.ngc_ad = ngc_ad;
    a.ws = ws; a.out = out;

    lif_k<<<(N_PV + N_SST + N_VIP + N_NGC + 255) / 256, 256, 0, stream>>>(a);
}

// Round 7
// 53.451 us; speedup vs baseline: 2.0693x; 2.0693x over previous
//
#include <hip/hip_runtime.h>
#include <math.h>

#define N_PYR 30000
#define N_PV  3000
#define N_SST 2250
#define N_VIP 1500
#define N_NGC 750
#define N_BIG (N_VIP + N_NGC)   // 2250 big rows (K = 30000)

#define DT    0.5f
#define E_E   3.0f
#define E_I   (-0.5f)
#define NIC_DECAY 0.9900498337491681f   // exp(-0.5/50)
#define MUS_DECAY 0.9975031223974601f   // exp(-0.5/200)

// R4 structure: 4 rows/block x 4 K-chunks for big rows, 4 rows/block for gap.
#define BIG_QUADS   ((N_BIG + 3) / 4)        // 563 (last quad has 2 rows)
#define N_CHUNKS    4
#define KCHUNK      (N_PYR / N_CHUNKS)       // 7500 floats
#define BIG_BLOCKS  (BIG_QUADS * N_CHUNKS)   // 2252
#define GAP_BLOCKS  (N_PV / 4)               // 750
#define VIP_QUADS   (N_VIP / 4)              // 375 (clean split: 1500 % 4 == 0)

// ws layout: partials[chunk][big_row] then gap results
#define WS_GAP (N_CHUNKS * N_BIG)

// native clang vector type — required by __builtin_nontemporal_load
typedef float f4n __attribute__((ext_vector_type(4)));

__device__ __forceinline__ float dot4(const f4n w, const f4n x) {
    return w.x * x.x + w.y * x.y + w.z * x.z + w.w * x.w;
}
__device__ __forceinline__ float sum4(const f4n w) {
    return w.x + w.y + w.z + w.w;
}

// Weight-stream accumulator. NT=true marks weight loads non-temporal (nt flag)
// so the 180 MB w_lr_vip stream does not evict the 126 MB ngc+gap working set
// from L3 between graph replays.
template<bool IS_GAP, bool NT>
__device__ __forceinline__ void accum_rows(
    const f4n* __restrict__ w0, const f4n* __restrict__ w1,
    const f4n* __restrict__ w2, const f4n* __restrict__ w3,
    const f4n* __restrict__ xv, int n4, int t,
    float& a0, float& a1, float& a2, float& a3,
    float& s0, float& s1, float& s2, float& s3)
{
    auto LD = [](const f4n* p) -> f4n {
        if constexpr (NT) return __builtin_nontemporal_load(p);
        else return *p;
    };

    int i = t;
    for (; i + 256 < n4; i += 512) {
        const f4n xA = xv[i];
        const f4n xB = xv[i + 256];
        const f4n wA0 = LD(w0 + i);       const f4n wA1 = LD(w1 + i);
        const f4n wA2 = LD(w2 + i);       const f4n wA3 = LD(w3 + i);
        const f4n wB0 = LD(w0 + i + 256); const f4n wB1 = LD(w1 + i + 256);
        const f4n wB2 = LD(w2 + i + 256); const f4n wB3 = LD(w3 + i + 256);
        a0 += dot4(wA0, xA) + dot4(wB0, xB);
        a1 += dot4(wA1, xA) + dot4(wB1, xB);
        a2 += dot4(wA2, xA) + dot4(wB2, xB);
        a3 += dot4(wA3, xA) + dot4(wB3, xB);
        if constexpr (IS_GAP) {
            s0 += sum4(wA0) + sum4(wB0);
            s1 += sum4(wA1) + sum4(wB1);
            s2 += sum4(wA2) + sum4(wB2);
            s3 += sum4(wA3) + sum4(wB3);
        }
    }
    if (i < n4) {
        const f4n xA = xv[i];
        const f4n wA0 = LD(w0 + i); const f4n wA1 = LD(w1 + i);
        const f4n wA2 = LD(w2 + i); const f4n wA3 = LD(w3 + i);
        a0 += dot4(wA0, xA);
        a1 += dot4(wA1, xA);
        a2 += dot4(wA2, xA);
        a3 += dot4(wA3, xA);
        if constexpr (IS_GAP) {
            s0 += sum4(wA0); s1 += sum4(wA1);
            s2 += sum4(wA2); s3 += sum4(wA3);
        }
    }
}

__global__ __launch_bounds__(256) void matvec_k(
    const float* __restrict__ w_vip, const float* __restrict__ w_ngc,
    const float* __restrict__ w_gap, const float* __restrict__ lre,
    const float* __restrict__ prev, float* __restrict__ ws)
{
    const int b = blockIdx.x;
    const int t = threadIdx.x;

    const f4n* w0;
    const f4n* w1;
    const f4n* w2;
    const f4n* w3;
    const f4n* xv;
    int n4, r0, dst, nv;
    bool is_gap = false;
    bool is_nt  = false;

    if (b < BIG_BLOCKS) {
        const int q     = b >> 2;
        const int chunk = b & 3;
        r0 = 4 * q;
        nv = (N_BIG - r0 < 4) ? (N_BIG - r0) : 4;
        is_nt = (q < VIP_QUADS);            // pure-VIP quads -> nt weight stream
        const float* bp[4];
        #pragma unroll
        for (int k = 0; k < 4; ++k) {
            int rr = r0 + k; if (rr > N_BIG - 1) rr = N_BIG - 1;
            const float* base = (rr < N_VIP)
                ? (w_vip + (size_t)rr * N_PYR)
                : (w_ngc + (size_t)(rr - N_VIP) * N_PYR);
            bp[k] = base + chunk * KCHUNK;
        }
        w0 = (const f4n*)bp[0]; w1 = (const f4n*)bp[1];
        w2 = (const f4n*)bp[2]; w3 = (const f4n*)bp[3];
        xv = (const f4n*)(lre + chunk * KCHUNK);
        n4 = KCHUNK / 4;                    // 1875
        dst = chunk * N_BIG + r0;
    } else {
        const int g = b - BIG_BLOCKS;
        r0 = 4 * g;
        nv = 4;
        w0 = (const f4n*)(w_gap + (size_t)r0 * N_PV);
        w1 = (const f4n*)(w_gap + (size_t)(r0 + 1) * N_PV);
        w2 = (const f4n*)(w_gap + (size_t)(r0 + 2) * N_PV);
        w3 = (const f4n*)(w_gap + (size_t)(r0 + 3) * N_PV);
        xv = (const f4n*)prev;
        n4 = N_PV / 4;                      // 750
        is_gap = true;
        dst = WS_GAP + r0;
    }

    float a0 = 0.f, a1 = 0.f, a2 = 0.f, a3 = 0.f;
    float s0 = 0.f, s1 = 0.f, s2 = 0.f, s3 = 0.f;

    if (is_gap) {
        accum_rows<true,  false>(w0, w1, w2, w3, xv, n4, t, a0, a1, a2, a3, s0, s1, s2, s3);
    } else if (is_nt) {
        accum_rows<false, true >(w0, w1, w2, w3, xv, n4, t, a0, a1, a2, a3, s0, s1, s2, s3);
    } else {
        accum_rows<false, false>(w0, w1, w2, w3, xv, n4, t, a0, a1, a2, a3, s0, s1, s2, s3);
    }

    #pragma unroll
    for (int off = 32; off > 0; off >>= 1) {
        a0 += __shfl_down(a0, off, 64);
        a1 += __shfl_down(a1, off, 64);
        a2 += __shfl_down(a2, off, 64);
        a3 += __shfl_down(a3, off, 64);
        s0 += __shfl_down(s0, off, 64);
        s1 += __shfl_down(s1, off, 64);
        s2 += __shfl_down(s2, off, 64);
        s3 += __shfl_down(s3, off, 64);
    }

    __shared__ float sm[4][8];
    const int wid = t >> 6, lane = t & 63;
    if (lane == 0) {
        sm[wid][0] = a0; sm[wid][1] = a1; sm[wid][2] = a2; sm[wid][3] = a3;
        sm[wid][4] = s0; sm[wid][5] = s1; sm[wid][6] = s2; sm[wid][7] = s3;
    }
    __syncthreads();
    if (t < nv) {
        float a = sm[0][t] + sm[1][t] + sm[2][t] + sm[3][t];
        if (is_gap) {
            const float rs = sm[0][4 + t] + sm[1][4 + t] + sm[2][4 + t] + sm[3][4 + t];
            a -= prev[r0 + t] * rs;
        }
        ws[dst + t] = a;
    }
}

// ---------------------------------------------------------------------------
// Kernel 2: LIF update for all 7500 interneurons.
// ---------------------------------------------------------------------------
struct LifArgs {
    const float *pv_g_exc, *pv_g_inh, *sst_g_exc, *sst_g_inh;
    const float *vip_g_exc, *vip_g_inh, *ngc_g_exc, *ngc_g_inh;
    const float *ffe, *ach, *nic, *mus;
    const float *pv_gL, *pv_tau, *pv_vth, *pv_v, *pv_ad;
    const float *sst_gL, *sst_tau, *sst_vth, *sst_v, *sst_ad;
    const float *vip_gL, *vip_tau, *vip_vth, *vip_v, *vip_ad;
    const float *ngc_gL, *ngc_tau, *ngc_vth, *ngc_v, *ngc_ad;
    const float *ws;
    float *out;
};

__device__ __forceinline__ void lif_step(
    float v, float adapt, float gE, float gI, float iex,
    float gL, float tau, float vth, float& spk, float& vout)
{
    const float C = gL * tau;
    const float I = gL * (0.0f - v) + gE * (E_E - v) + gI * (E_I - v) + iex;
    const float v_new = v + DT * I / C;
    spk = (v_new >= vth + adapt) ? 1.0f : 0.0f;
    vout = (spk > 0.0f) ? 0.0f : v_new;
}

__global__ __launch_bounds__(256) void lif_k(LifArgs a)
{
    const int i = blockIdx.x * 256 + threadIdx.x;
    const int total = N_PV + N_SST + N_VIP + N_NGC;  // 7500
    if (i >= total) return;

    float spk, vout;
    if (i < N_PV) {
        const int j = i;
        const float gE = a.pv_g_exc[j] + a.ffe[j];
        const float iex = a.ws[WS_GAP + j];
        lif_step(a.pv_v[j], a.pv_ad[j], gE, a.pv_g_inh[j], iex,
                 a.pv_gL[j], a.pv_tau[j], a.pv_vth[j], spk, vout);
        a.out[j] = spk;
        a.out[total + j] = vout;
    } else if (i < N_PV + N_SST) {
        const int j = i - N_PV;
        lif_step(a.sst_v[j], a.sst_ad[j], a.sst_g_exc[j], a.sst_g_inh[j], 0.0f,
                 a.sst_gL[j], a.sst_tau[j], a.sst_vth[j], spk, vout);
        a.out[N_PV + j] = spk;
        a.out[total + N_PV + j] = vout;
    } else if (i < N_PV + N_SST + N_VIP) {
        const int j = i - N_PV - N_SST;
        const float nic = a.nic[j] * NIC_DECAY + a.ach[0];
        const float lr = a.ws[j] + a.ws[N_BIG + j]
                       + a.ws[2 * N_BIG + j] + a.ws[3 * N_BIG + j];
        const float gE = a.vip_g_exc[j] + lr + nic * 0.25f;
        lif_step(a.vip_v[j], a.vip_ad[j], gE, a.vip_g_inh[j], 0.0f,
                 a.vip_gL[j], a.vip_tau[j], a.vip_vth[j], spk, vout);
        a.out[N_PV + N_SST + j] = spk;
        a.out[total + N_PV + N_SST + j] = vout;
    } else {
        const int j = i - N_PV - N_SST - N_VIP;
        const float mus = a.mus[j] * MUS_DECAY + a.ach[0];
        const int r = N_VIP + j;
        const float lr = a.ws[r] + a.ws[N_BIG + r]
                       + a.ws[2 * N_BIG + r] + a.ws[3 * N_BIG + r];
        const float gE = a.ngc_g_exc[j] + lr + mus * 0.2f;
        lif_step(a.ngc_v[j], a.ngc_ad[j], gE, a.ngc_g_inh[j], 0.0f,
                 a.ngc_gL[j], a.ngc_tau[j], a.ngc_vth[j], spk, vout);
        a.out[N_PV + N_SST + N_VIP + j] = spk;
        a.out[total + N_PV + N_SST + N_VIP + j] = vout;
    }
}

extern "C" void kernel_launch(void* const* d_in, const int* in_sizes, int n_in,
                              void* d_out, int out_size, void* d_ws, size_t ws_size,
                              hipStream_t stream) {
    const float* pv_g_exc  = (const float*)d_in[0];
    const float* pv_g_inh  = (const float*)d_in[1];
    const float* sst_g_exc = (const float*)d_in[2];
    const float* sst_g_inh = (const float*)d_in[3];
    const float* vip_g_exc = (const float*)d_in[4];
    const float* vip_g_inh = (const float*)d_in[5];
    const float* ngc_g_exc = (const float*)d_in[6];
    const float* ngc_g_inh = (const float*)d_in[7];
    const float* ffe       = (const float*)d_in[8];
    const float* lre       = (const float*)d_in[9];
    const float* ach       = (const float*)d_in[10];
    const float* w_lr_vip  = (const float*)d_in[11];
    const float* w_lr_ngc  = (const float*)d_in[12];
    const float* w_pv_gap  = (const float*)d_in[13];
    const float* prev_pv   = (const float*)d_in[14];
    const float* nic_trace = (const float*)d_in[15];
    const float* mus_trace = (const float*)d_in[16];

    const float* pv_gL   = (const float*)d_in[17];
    const float* pv_tau  = (const float*)d_in[18];
    const float* pv_vth  = (const float*)d_in[19];
    const float* pv_v    = (const float*)d_in[21];
    const float* pv_ad   = (const float*)d_in[22];

    const float* sst_gL   = (const float*)d_in[23];
    const float* sst_tau  = (const float*)d_in[24];
    const float* sst_vth  = (const float*)d_in[25];
    const float* sst_v    = (const float*)d_in[27];
    const float* sst_ad   = (const float*)d_in[28];

    const float* vip_gL   = (const float*)d_in[29];
    const float* vip_tau  = (const float*)d_in[30];
    const float* vip_vth  = (const float*)d_in[31];
    const float* vip_v    = (const float*)d_in[33];
    const float* vip_ad   = (const float*)d_in[34];

    const float* ngc_gL   = (const float*)d_in[35];
    const float* ngc_tau  = (const float*)d_in[36];
    const float* ngc_vth  = (const float*)d_in[37];
    const float* ngc_v    = (const float*)d_in[39];
    const float* ngc_ad   = (const float*)d_in[40];

    float* ws  = (float*)d_ws;
    float* out = (float*)d_out;

    matvec_k<<<BIG_BLOCKS + GAP_BLOCKS, 256, 0, stream>>>(
        w_lr_vip, w_lr_ngc, w_pv_gap, lre, prev_pv, ws);

    LifArgs a;
    a.pv_g_exc = pv_g_exc; a.pv_g_inh = pv_g_inh;
    a.sst_g_exc = sst_g_exc; a.sst_g_inh = sst_g_inh;
    a.vip_g_exc = vip_g_exc; a.vip_g_inh = vip_g_inh;
    a.ngc_g_exc = ngc_g_exc; a.ngc_g_inh = ngc_g_inh;
    a.ffe = ffe; a.ach = ach; a.nic = nic_trace; a.mus = mus_trace;
    a.pv_gL = pv_gL; a.pv_tau = pv_tau; a.pv_vth = pv_vth;
    a.pv_v = pv_v; a.pv_ad = pv_ad;
    a.sst_gL = sst_gL; a.sst_tau = sst_tau; a.sst_vth = sst_vth;
    a.sst_v = sst_v; a.sst_ad = sst_ad;
    a.vip_gL = vip_gL; a.vip_tau = vip_tau; a.vip_vth = vip_vth;
    a.vip_v = vip_v; a.vip_ad = vip_ad;
    a.ngc_gL = ngc_gL; a.ngc_tau = ngc_tau; a.ngc_vth = ngc_vth;
    a.ngc_v = ngc_v; a.ngc_ad = ngc_ad;
    a.ws = ws; a.out = out;

    lif_k<<<(N_PV + N_SST + N_VIP + N_NGC + 255) / 256, 256, 0, stream>>>(a);
}